// Round 1
// baseline (444.093 us; speedup 1.0000x reference)
//
#include <hip/hip_runtime.h>

#define HEADS  16
#define DH     64
#define NBATCH 2
#define SEQ    2048
#define DMODEL 1024

typedef unsigned short u16;
typedef unsigned int   u32;
typedef unsigned long long u64;

typedef __attribute__((ext_vector_type(8))) short short8v;   // 8 bf16
typedef __attribute__((ext_vector_type(4))) float floatx4;

__device__ __forceinline__ u16 f2bf(float f) {
    u32 u = __float_as_uint(f);
    return (u16)((u + 0x7fffu + ((u >> 16) & 1u)) >> 16);
}
__device__ __forceinline__ float bf2f(u16 h) {
    return __uint_as_float(((u32)h) << 16);
}

// ---------------- split x into hi/lo bf16 ----------------
__global__ void k_split(const float* __restrict__ in, u16* __restrict__ hi,
                        u16* __restrict__ lo, int n4) {
    int i = blockIdx.x * blockDim.x + threadIdx.x;
    if (i >= n4) return;
    float4 v = reinterpret_cast<const float4*>(in)[i];
    ushort4 hv, lv;
    hv.x = f2bf(v.x); hv.y = f2bf(v.y); hv.z = f2bf(v.z); hv.w = f2bf(v.w);
    lv.x = f2bf(v.x - bf2f(hv.x));
    lv.y = f2bf(v.y - bf2f(hv.y));
    lv.z = f2bf(v.z - bf2f(hv.z));
    lv.w = f2bf(v.w - bf2f(hv.w));
    reinterpret_cast<ushort4*>(hi)[i] = hv;
    reinterpret_cast<ushort4*>(lo)[i] = lv;
}

// ---------------- transpose + split: in[R][C] f32 -> hiT/loT [C][R] bf16 ----------------
__global__ void k_tsplit(const float* __restrict__ in, u16* __restrict__ hiT,
                         u16* __restrict__ loT, int R, int C, int write_lo) {
    __shared__ float tile[64][65];
    int c0 = blockIdx.x * 64, r0 = blockIdx.y * 64;
    int t = threadIdx.x;
    int lr = t >> 4;          // 0..15
    int lc = (t & 15) * 4;    // 0..60
    for (int i = 0; i < 4; i++) {
        int r = lr + i * 16;
        float4 v = *reinterpret_cast<const float4*>(&in[(size_t)(r0 + r) * C + c0 + lc]);
        tile[r][lc] = v.x; tile[r][lc + 1] = v.y; tile[r][lc + 2] = v.z; tile[r][lc + 3] = v.w;
    }
    __syncthreads();
    for (int i = 0; i < 4; i++) {
        int cc = lr + i * 16;                       // local col -> output row c0+cc
        float vs0 = tile[lc + 0][cc], vs1 = tile[lc + 1][cc];
        float vs2 = tile[lc + 2][cc], vs3 = tile[lc + 3][cc];
        ushort4 hv, lv;
        hv.x = f2bf(vs0); hv.y = f2bf(vs1); hv.z = f2bf(vs2); hv.w = f2bf(vs3);
        *reinterpret_cast<ushort4*>(&hiT[(size_t)(c0 + cc) * R + r0 + lc]) = hv;
        if (write_lo) {
            lv.x = f2bf(vs0 - bf2f(hv.x)); lv.y = f2bf(vs1 - bf2f(hv.y));
            lv.z = f2bf(vs2 - bf2f(hv.z)); lv.w = f2bf(vs3 - bf2f(hv.w));
            *reinterpret_cast<ushort4*>(&loT[(size_t)(c0 + cc) * R + r0 + lc]) = lv;
        }
    }
}

// ---------------- bit-pack mask (int32 0/1, True = masked) ----------------
__global__ void k_maskpack(const int* __restrict__ m, u64* __restrict__ bits) {
    int i = blockIdx.x * 256 + threadIdx.x;
    u64 b = __ballot(m[i] != 0);
    if ((threadIdx.x & 63) == 0) bits[((u32)i) >> 6] = b;
}

// ---------------- QKV GEMM: [4096,1024] x [1024,3072], 3-term split MFMA for q/k ----------------
__global__ __launch_bounds__(256, 2) void k_qkv(
    const u16* __restrict__ xh, const u16* __restrict__ xl,
    const u16* __restrict__ whT, const u16* __restrict__ wlT,
    u16* __restrict__ qh, u16* __restrict__ ql,
    u16* __restrict__ kh, u16* __restrict__ kl,
    u16* __restrict__ vt)
{
    __shared__ __attribute__((aligned(16))) u16 sA[2][128][72];
    __shared__ __attribute__((aligned(16))) u16 sB[2][128][72];
    int n0 = blockIdx.x * 128;
    int m0 = blockIdx.y * 128;
    bool is_v = (n0 >= 2 * DMODEL);
    int tid = threadIdx.x;
    int wave = tid >> 6, lane = tid & 63;
    int wm = (wave >> 1) * 64, wn = (wave & 1) * 64;
    int lrow = lane & 15, lgrp = lane >> 4;

    floatx4 acc[4][4];
    for (int i = 0; i < 4; i++) for (int j = 0; j < 4; j++) acc[i][j] = (floatx4){0.f, 0.f, 0.f, 0.f};

    int sr = tid >> 1;
    int sc = (tid & 1) * 32;

    for (int k0 = 0; k0 < DMODEL; k0 += 64) {
        const u16* pxh = xh + (size_t)(m0 + sr) * DMODEL + k0 + sc;
        const u16* pwh = whT + (size_t)(n0 + sr) * DMODEL + k0 + sc;
        for (int i = 0; i < 4; i++) {
            *reinterpret_cast<int4*>(&sA[0][sr][sc + i * 8]) = *reinterpret_cast<const int4*>(pxh + i * 8);
            *reinterpret_cast<int4*>(&sB[0][sr][sc + i * 8]) = *reinterpret_cast<const int4*>(pwh + i * 8);
        }
        if (!is_v) {
            const u16* pxl = xl + (size_t)(m0 + sr) * DMODEL + k0 + sc;
            const u16* pwl = wlT + (size_t)(n0 + sr) * DMODEL + k0 + sc;
            for (int i = 0; i < 4; i++) {
                *reinterpret_cast<int4*>(&sA[1][sr][sc + i * 8]) = *reinterpret_cast<const int4*>(pxl + i * 8);
                *reinterpret_cast<int4*>(&sB[1][sr][sc + i * 8]) = *reinterpret_cast<const int4*>(pwl + i * 8);
            }
        }
        __syncthreads();
        for (int ks = 0; ks < 2; ks++) {
            short8v ah[4], bh_[4], al[4], bl_[4];
            for (int i = 0; i < 4; i++) {
                ah[i]  = *reinterpret_cast<const short8v*>(&sA[0][wm + i * 16 + lrow][ks * 32 + lgrp * 8]);
                bh_[i] = *reinterpret_cast<const short8v*>(&sB[0][wn + i * 16 + lrow][ks * 32 + lgrp * 8]);
            }
            if (!is_v) {
                for (int i = 0; i < 4; i++) {
                    al[i]  = *reinterpret_cast<const short8v*>(&sA[1][wm + i * 16 + lrow][ks * 32 + lgrp * 8]);
                    bl_[i] = *reinterpret_cast<const short8v*>(&sB[1][wn + i * 16 + lrow][ks * 32 + lgrp * 8]);
                }
            }
            for (int i = 0; i < 4; i++)
                for (int j = 0; j < 4; j++) {
                    acc[i][j] = __builtin_amdgcn_mfma_f32_16x16x32_bf16(ah[i], bh_[j], acc[i][j], 0, 0, 0);
                    if (!is_v) {
                        acc[i][j] = __builtin_amdgcn_mfma_f32_16x16x32_bf16(ah[i], bl_[j], acc[i][j], 0, 0, 0);
                        acc[i][j] = __builtin_amdgcn_mfma_f32_16x16x32_bf16(al[i], bh_[j], acc[i][j], 0, 0, 0);
                    }
                }
        }
        __syncthreads();
    }
    // epilogue: scatter into q/k (hi/lo, x8 folded into q) and transposed V
    for (int j = 0; j < 4; j++) {
        int c = n0 + wn + j * 16 + lrow;
        int sel = c >> 10;
        int hcol = c & 1023;
        int hh = hcol >> 6, d = hcol & 63;
        for (int i = 0; i < 4; i++) {
            int mbase = m0 + wm + i * 16 + lgrp * 4;
            int bb = mbase >> 11;
            int nn = mbase & 2047;
            int bh = bb * HEADS + hh;
            if (sel == 2) {
                ushort4 pv;
                pv.x = f2bf(acc[i][j][0]); pv.y = f2bf(acc[i][j][1]);
                pv.z = f2bf(acc[i][j][2]); pv.w = f2bf(acc[i][j][3]);
                *reinterpret_cast<ushort4*>(&vt[((size_t)bh * DH + d) * SEQ + nn]) = pv;
            } else {
                u16* oh = (sel == 0) ? qh : kh;
                u16* ol = (sel == 0) ? ql : kl;
                float sc8 = (sel == 0) ? 8.0f : 1.0f;   // fold scores * sqrt(dh) into q
                for (int r = 0; r < 4; r++) {
                    float v = acc[i][j][r] * sc8;
                    u16 hv = f2bf(v);
                    u16 lv = f2bf(v - bf2f(hv));
                    size_t addr = ((size_t)bh * SEQ + nn + r) * DH + d;
                    oh[addr] = hv; ol[addr] = lv;
                }
            }
        }
    }
}

// ---------------- attention: per (bh, 64 q-rows); 2-pass online softmax ----------------
__global__ __launch_bounds__(256, 2) void k_attn(
    const u16* __restrict__ qh, const u16* __restrict__ ql,
    const u16* __restrict__ kh, const u16* __restrict__ kl,
    const u16* __restrict__ vt, const u32* __restrict__ mb,
    float* __restrict__ attn, u16* __restrict__ ctx)
{
    __shared__ __attribute__((aligned(16))) u16 sK[2][128][72];
    __shared__ __attribute__((aligned(16))) u16 sV[64][136];
    __shared__ __attribute__((aligned(16))) u16 sP[64][136];
    __shared__ u32 sMask[64][4];
    __shared__ float sML[2][4][64];

    int bh = blockIdx.y;
    int b = bh >> 4, hh = bh & 15;
    int q0 = blockIdx.x * 64;
    int tid = threadIdx.x, wave = tid >> 6, lane = tid & 63;
    int lrow = lane & 15, lgrp = lane >> 4;
    int sr = tid >> 1, scol = (tid & 1) * 32;
    int mr = tid >> 2, mw = tid & 3;

    // Q fragments (B-operand of K·Q^T), hi/lo
    short8v qfh[4][2], qfl[4][2];
    for (int nt = 0; nt < 4; nt++) {
        int qr = q0 + nt * 16 + lrow;
        const u16* pq = qh + ((size_t)bh * SEQ + qr) * DH + lgrp * 8;
        const u16* pl = ql + ((size_t)bh * SEQ + qr) * DH + lgrp * 8;
        for (int ks = 0; ks < 2; ks++) {
            qfh[nt][ks] = *reinterpret_cast<const short8v*>(pq + ks * 32);
            qfl[nt][ks] = *reinterpret_cast<const short8v*>(pl + ks * 32);
        }
    }

#define STAGE_K_MASK() do { \
        const u16* ph_ = kh + ((size_t)bh * SEQ + kt * 128 + sr) * DH + scol; \
        const u16* pl_ = kl + ((size_t)bh * SEQ + kt * 128 + sr) * DH + scol; \
        for (int i_ = 0; i_ < 4; i_++) { \
            *reinterpret_cast<int4*>(&sK[0][sr][scol + i_ * 8]) = *reinterpret_cast<const int4*>(ph_ + i_ * 8); \
            *reinterpret_cast<int4*>(&sK[1][sr][scol + i_ * 8]) = *reinterpret_cast<const int4*>(pl_ + i_ * 8); \
        } \
        sMask[mr][mw] = mb[((size_t)b * SEQ + q0 + mr) * 64 + kt * 4 + mw]; \
    } while (0)

#define COMPUTE_ST() do { \
        for (int mt_ = 0; mt_ < 2; mt_++) for (int nt_ = 0; nt_ < 4; nt_++) sacc[mt_][nt_] = (floatx4){0.f,0.f,0.f,0.f}; \
        for (int ks_ = 0; ks_ < 2; ks_++) { \
            short8v kfh[2], kfl[2]; \
            for (int mt_ = 0; mt_ < 2; mt_++) { \
                kfh[mt_] = *reinterpret_cast<const short8v*>(&sK[0][wave * 32 + mt_ * 16 + lrow][ks_ * 32 + lgrp * 8]); \
                kfl[mt_] = *reinterpret_cast<const short8v*>(&sK[1][wave * 32 + mt_ * 16 + lrow][ks_ * 32 + lgrp * 8]); \
            } \
            for (int mt_ = 0; mt_ < 2; mt_++) for (int nt_ = 0; nt_ < 4; nt_++) { \
                sacc[mt_][nt_] = __builtin_amdgcn_mfma_f32_16x16x32_bf16(kfh[mt_], qfh[nt_][ks_], sacc[mt_][nt_], 0, 0, 0); \
                sacc[mt_][nt_] = __builtin_amdgcn_mfma_f32_16x16x32_bf16(kfh[mt_], qfl[nt_][ks_], sacc[mt_][nt_], 0, 0, 0); \
                sacc[mt_][nt_] = __builtin_amdgcn_mfma_f32_16x16x32_bf16(kfl[mt_], qfh[nt_][ks_], sacc[mt_][nt_], 0, 0, 0); \
            } \
        } \
    } while (0)

    float m_run[4], l_run[4];
    for (int nt = 0; nt < 4; nt++) { m_run[nt] = -3.0e38f; l_run[nt] = 0.f; }

    // ---- pass A: online (m, l) per wave-stripe ----
    for (int kt = 0; kt < 16; kt++) {
        STAGE_K_MASK();
        __syncthreads();
        floatx4 sacc[2][4];
        COMPUTE_ST();
        for (int nt = 0; nt < 4; nt++) {
            u32 mwrd = sMask[nt * 16 + lrow][wave];
            float s[8];
            for (int mt = 0; mt < 2; mt++)
                for (int r = 0; r < 4; r++) {
                    int bit = mt * 16 + lgrp * 4 + r;
                    s[mt * 4 + r] = ((mwrd >> bit) & 1u) ? -1e9f : sacc[mt][nt][r];
                }
            float tmax = s[0];
            for (int u = 1; u < 8; u++) tmax = fmaxf(tmax, s[u]);
            tmax = fmaxf(tmax, __shfl_xor(tmax, 16));
            tmax = fmaxf(tmax, __shfl_xor(tmax, 32));
            float mn = fmaxf(m_run[nt], tmax);
            float ssum = 0.f;
            for (int u = 0; u < 8; u++) ssum += __expf(s[u] - mn);
            ssum += __shfl_xor(ssum, 16);
            ssum += __shfl_xor(ssum, 32);
            l_run[nt] = l_run[nt] * __expf(m_run[nt] - mn) + ssum;
            m_run[nt] = mn;
        }
        __syncthreads();
    }
    // merge (m, l) across waves
    if (lane < 16) {
        for (int nt = 0; nt < 4; nt++) {
            sML[0][wave][nt * 16 + lane] = m_run[nt];
            sML[1][wave][nt * 16 + lane] = l_run[nt];
        }
    }
    __syncthreads();
    float m_fin[4], rl[4];
    for (int nt = 0; nt < 4; nt++) {
        int qr = nt * 16 + lrow;
        float m4 = sML[0][0][qr];
        for (int w = 1; w < 4; w++) m4 = fmaxf(m4, sML[0][w][qr]);
        float ls = 0.f;
        for (int w = 0; w < 4; w++) ls += sML[1][w][qr] * __expf(sML[0][w][qr] - m4);
        m_fin[nt] = m4;
        rl[nt] = 1.0f / ls;
    }

    floatx4 cacc[4];
    for (int j = 0; j < 4; j++) cacc[j] = (floatx4){0.f, 0.f, 0.f, 0.f};

    // ---- pass B: recompute S, write attn, PV ----
    for (int kt = 0; kt < 16; kt++) {
        STAGE_K_MASK();
        {
            int vd = tid >> 2, vq = (tid & 3) * 32;
            const u16* pv = vt + ((size_t)bh * DH + vd) * SEQ + kt * 128 + vq;
            for (int i = 0; i < 4; i++)
                *reinterpret_cast<int4*>(&sV[vd][vq + i * 8]) = *reinterpret_cast<const int4*>(pv + i * 8);
        }
        __syncthreads();
        floatx4 sacc[2][4];
        COMPUTE_ST();
        for (int nt = 0; nt < 4; nt++) {
            u32 mwrd = sMask[nt * 16 + lrow][wave];
            int qr = q0 + nt * 16 + lrow;
            for (int mt = 0; mt < 2; mt++) {
                float4 pf;
                float* pp = &pf.x;
                for (int r = 0; r < 4; r++) {
                    int bit = mt * 16 + lgrp * 4 + r;
                    float sv = ((mwrd >> bit) & 1u) ? -1e9f : sacc[mt][nt][r];
                    pp[r] = __expf(sv - m_fin[nt]) * rl[nt];
                }
                int kc = kt * 128 + wave * 32 + mt * 16 + lgrp * 4;
                *reinterpret_cast<float4*>(&attn[((size_t)bh * SEQ + qr) * SEQ + kc]) = pf;
                ushort4 pb;
                pb.x = f2bf(pp[0]); pb.y = f2bf(pp[1]); pb.z = f2bf(pp[2]); pb.w = f2bf(pp[3]);
                *reinterpret_cast<ushort4*>(&sP[nt * 16 + lrow][wave * 32 + mt * 16 + lgrp * 4]) = pb;
            }
        }
        __syncthreads();
        for (int ks = 0; ks < 4; ks++) {
            short8v pfrag = *reinterpret_cast<const short8v*>(&sP[wave * 16 + lrow][ks * 32 + lgrp * 8]);
            for (int j = 0; j < 4; j++) {
                short8v vfrag = *reinterpret_cast<const short8v*>(&sV[j * 16 + lrow][ks * 32 + lgrp * 8]);
                cacc[j] = __builtin_amdgcn_mfma_f32_16x16x32_bf16(pfrag, vfrag, cacc[j], 0, 0, 0);
            }
        }
        __syncthreads();
    }
    // write context (bf16) into [b, n, h*dh]
    for (int j = 0; j < 4; j++) {
        int d = j * 16 + lrow;
        for (int r = 0; r < 4; r++) {
            int nn = q0 + wave * 16 + lgrp * 4 + r;
            ctx[((size_t)b * SEQ + nn) * DMODEL + hh * 64 + d] = f2bf(cacc[j][r]);
        }
    }
#undef STAGE_K_MASK
#undef COMPUTE_ST
}

// ---------------- out = ctx @ Wfc ----------------
__global__ __launch_bounds__(256, 2) void k_out(
    const u16* __restrict__ ctx, const u16* __restrict__ wfcT, float* __restrict__ out)
{
    __shared__ __attribute__((aligned(16))) u16 sA[128][72];
    __shared__ __attribute__((aligned(16))) u16 sB[128][72];
    int n0 = blockIdx.x * 128;
    int m0 = blockIdx.y * 128;
    int tid = threadIdx.x;
    int wave = tid >> 6, lane = tid & 63;
    int wm = (wave >> 1) * 64, wn = (wave & 1) * 64;
    int lrow = lane & 15, lgrp = lane >> 4;

    floatx4 acc[4][4];
    for (int i = 0; i < 4; i++) for (int j = 0; j < 4; j++) acc[i][j] = (floatx4){0.f, 0.f, 0.f, 0.f};

    int sr = tid >> 1;
    int sc = (tid & 1) * 32;

    for (int k0 = 0; k0 < DMODEL; k0 += 64) {
        const u16* pa = ctx + (size_t)(m0 + sr) * DMODEL + k0 + sc;
        const u16* pb = wfcT + (size_t)(n0 + sr) * DMODEL + k0 + sc;
        for (int i = 0; i < 4; i++) {
            *reinterpret_cast<int4*>(&sA[sr][sc + i * 8]) = *reinterpret_cast<const int4*>(pa + i * 8);
            *reinterpret_cast<int4*>(&sB[sr][sc + i * 8]) = *reinterpret_cast<const int4*>(pb + i * 8);
        }
        __syncthreads();
        for (int ks = 0; ks < 2; ks++) {
            short8v af[4], bf[4];
            for (int i = 0; i < 4; i++) {
                af[i] = *reinterpret_cast<const short8v*>(&sA[wm + i * 16 + lrow][ks * 32 + lgrp * 8]);
                bf[i] = *reinterpret_cast<const short8v*>(&sB[wn + i * 16 + lrow][ks * 32 + lgrp * 8]);
            }
            for (int i = 0; i < 4; i++)
                for (int j = 0; j < 4; j++)
                    acc[i][j] = __builtin_amdgcn_mfma_f32_16x16x32_bf16(af[i], bf[j], acc[i][j], 0, 0, 0);
        }
        __syncthreads();
    }
    for (int i = 0; i < 4; i++)
        for (int j = 0; j < 4; j++)
            for (int r = 0; r < 4; r++) {
                int m = m0 + wm + i * 16 + lgrp * 4 + r;
                int c = n0 + wn + j * 16 + lrow;
                out[(size_t)m * DMODEL + c] = acc[i][j][r];
            }
}

extern "C" void kernel_launch(void* const* d_in, const int* in_sizes, int n_in,
                              void* d_out, int out_size, void* d_ws, size_t ws_size,
                              hipStream_t stream) {
    const float* x    = (const float*)d_in[0];
    const int*   mask = (const int*)d_in[1];
    const float* wqkv = (const float*)d_in[2];
    const float* wfc  = (const float*)d_in[3];

    float* out  = (float*)d_out;
    float* attn = out + (size_t)NBATCH * SEQ * DMODEL;

    u16* xh   = (u16*)d_ws;                 // 4096*1024
    u16* xl   = xh + 4194304;
    u16* whT  = xl + 4194304;               // 3072*1024
    u16* wlT  = whT + 3145728;
    u16* wfcT = wlT + 3145728;              // 1024*1024
    u16* qh   = wfcT + 1048576;             // 32*2048*64 each
    u16* ql   = qh + 4194304;
    u16* kh   = ql + 4194304;
    u16* kl   = kh + 4194304;
    u16* vt   = kl + 4194304;
    u32* mbits = (u32*)(vt + 4194304);      // 2*2048*64 words
    u16* ctx  = xh;                         // overlay: x splits dead after k_qkv

    k_split<<<4096, 256, 0, stream>>>(x, xh, xl, 4194304 / 4);
    k_tsplit<<<dim3(48, 16), 256, 0, stream>>>(wqkv, whT, wlT, 1024, 3072, 1);
    k_tsplit<<<dim3(16, 16), 256, 0, stream>>>(wfc, wfcT, (u16*)nullptr, 1024, 1024, 0);
    k_maskpack<<<32768, 256, 0, stream>>>(mask, (u64*)mbits);
    k_qkv<<<dim3(24, 32), 256, 0, stream>>>(xh, xl, whT, wlT, qh, ql, kh, kl, vt);
    k_attn<<<dim3(32, 32), 256, 0, stream>>>(qh, ql, kh, kl, vt, mbits, attn, ctx);
    k_out<<<dim3(8, 32), 256, 0, stream>>>(ctx, wfcT, out);
}